// Round 7
// baseline (46709.732 us; speedup 1.0000x reference)
//
#include <hip/hip_runtime.h>
#include <math.h>

#define BB 128   // batch
#define TT 256   // time
#define DD 256   // input dims
#define UU 512   // units
#define RR 512   // ladder order

// ws layout (floats):
//   X0 [128*512] @ 0        x_t in X0 for even t, X1 for odd t
//   X1 [128*512] @ 65536
//   M  [128*256] @ 131072   m_{t-1} during x_kernel; m_t after m_kernel
//   HZ [128*512] @ 163840   zeros (h_{-1})
#define OFF_X0 0
#define OFF_X1 65536
#define OFF_M  131072
#define OFF_HZ 163840
#define WS_FLT 229376
#define WS_NEED_BYTES (WS_FLT * 4)

__global__ __launch_bounds__(256) void zero_kernel(float* __restrict__ p, int n)
{
    int i = blockIdx.x * 256 + threadIdx.x;
    if (i < n) p[i] = 0.0f;
}

// x_t = x_{t-1} @ AT + (inp_t + m_{t-1}) @ BT
// Bitwise model: each dot = ascending-k single-accumulator fmaf chain from 0;
// the two dot results combined by ONE f32 add (matches BLAS dot+dot then elementwise add).
__global__ __launch_bounds__(256) void x_kernel(
    const float* __restrict__ inputs, const float* __restrict__ AT,
    const float* __restrict__ BT,
    const float* __restrict__ xin, const float* __restrict__ m,
    float* __restrict__ xout, int t)
{
    const int row = blockIdx.x >> 1;
    const int c   = (blockIdx.x & 1) * 256 + threadIdx.x;
    const float* xr = xin + row * RR;
    float accA = 0.0f;
    for (int k = 0; k < RR; ++k)
        accA = fmaf(xr[k], AT[k * RR + c], accA);
    const float* ir = inputs + (row * TT + t) * DD;
    const float* mr = m + row * DD;
    float accB = 0.0f;
    for (int d = 0; d < DD; ++d) {
        float u = ir[d] + mr[d];              // u = inp_t + m_{t-1}, f32-rounded once
        accB = fmaf(u, BT[d * RR + c], accB);
    }
    xout[row * RR + c] = accA + accB;
}

// m_t = x_t @ CT  (ascending-k fmaf chain)
__global__ __launch_bounds__(256) void m_kernel(
    const float* __restrict__ CT, const float* __restrict__ x,
    float* __restrict__ m)
{
    const int row = blockIdx.x;
    const int c   = threadIdx.x;
    const float* xr = x + row * RR;
    float acc = 0.0f;
    for (int k = 0; k < RR; ++k)
        acc = fmaf(xr[k], CT[k * DD + c], acc);
    m[row * DD + c] = acc;
}

// h_t = tanh(((h_{t-1}@WyhT + x_t@WyxT) + (wfm*m_t)@WyfT) + by)
// Three separate ascending-k chains, combined left-associated as Python does.
__global__ __launch_bounds__(256) void h_kernel(
    const float* __restrict__ wfm, const float* __restrict__ by,
    const float* __restrict__ WyhT, const float* __restrict__ WyxT,
    const float* __restrict__ WyfT,
    const float* __restrict__ x,   // x_t
    const float* __restrict__ m,   // m_t
    const float* __restrict__ hz,  // zeros (h_{-1})
    float* __restrict__ out, int t)
{
    const int row = blockIdx.x >> 1;
    const int c   = (blockIdx.x & 1) * 256 + threadIdx.x;

    const float* hr = (t == 0) ? (hz + row * UU)
                               : (out + (row * TT + (t - 1)) * UU);
    float accH = 0.0f;
    for (int k = 0; k < UU; ++k)
        accH = fmaf(hr[k], WyhT[k * UU + c], accH);

    const float* xr = x + row * RR;
    float accX = 0.0f;
    for (int k = 0; k < RR; ++k)
        accX = fmaf(xr[k], WyxT[k * UU + c], accX);

    const float* mr = m + row * DD;
    float accF = 0.0f;
    for (int d = 0; d < DD; ++d) {
        float f = wfm[d] * mr[d];             // f = wfm * m_t, f32-rounded once
        accF = fmaf(f, WyfT[d * UU + c], accF);
    }

    float z = ((accH + accX) + accF) + by[c];
    out[(row * TT + t) * UU + c] = tanhf(z);
}

__global__ __launch_bounds__(64) void sentinel_kernel(float* __restrict__ out, float v)
{
    if (threadIdx.x == 0 && blockIdx.x == 0) out[0] = v;
}

extern "C" void kernel_launch(void* const* d_in, const int* in_sizes, int n_in,
                              void* d_out, int out_size, void* d_ws, size_t ws_size,
                              hipStream_t stream)
{
    const float* inputs = (const float*)d_in[0];
    const float* wfm    = (const float*)d_in[1];
    const float* WyhT   = (const float*)d_in[2];
    const float* WyxT   = (const float*)d_in[3];
    const float* WyfT   = (const float*)d_in[4];
    const float* by     = (const float*)d_in[5];
    const float* AT     = (const float*)d_in[6];
    const float* BT     = (const float*)d_in[7];
    const float* CT     = (const float*)d_in[8];
    float* out = (float*)d_out;
    float* ws  = (float*)d_ws;

    // Environment sentinels (absmax reveals code if triggered).
    double code = 0.0;
    static const int exp_sizes[9] = {8388608, 256, 262144, 262144, 131072,
                                     512, 262144, 131072, 131072};
    if (n_in != 9) {
        code = 3.0e6 + n_in;
    } else {
        for (int i = 0; i < 9; ++i)
            if (in_sizes[i] != exp_sizes[i]) { code = 2.0e6 + i * 1.0e4; break; }
    }
    if (code == 0.0 && out_size != BB * TT * UU)
        code = 4.0e6 + (double)(out_size / 10000);
    if (code == 0.0 && ws_size < (size_t)WS_NEED_BYTES)
        code = 1.0e6 + (double)(ws_size / 1024);
    if (code != 0.0) {
        sentinel_kernel<<<1, 64, 0, stream>>>(out, (float)code);
        return;
    }

    // Zero x_{-1} (X1), m_{-1} (M), h_{-1} (HZ); X0 written before read.
    zero_kernel<<<(WS_FLT + 255) / 256, 256, 0, stream>>>(ws, WS_FLT);

    for (int t = 0; t < TT; ++t) {
        const float* xin = ws + ((t & 1) ? OFF_X0 : OFF_X1);  // x_{t-1}
        float*       xo  = ws + ((t & 1) ? OFF_X1 : OFF_X0);  // x_t
        float*       M   = ws + OFF_M;
        x_kernel<<<256, 256, 0, stream>>>(inputs, AT, BT, xin, M, xo, t);
        m_kernel<<<128, 256, 0, stream>>>(CT, xo, M);
        h_kernel<<<256, 256, 0, stream>>>(wfm, by, WyhT, WyxT, WyfT,
                                          xo, M, ws + OFF_HZ, out, t);
    }
}

// Round 8
// 12659.751 us; speedup vs baseline: 3.6896x; 3.6896x over previous
//
#include <hip/hip_runtime.h>
#include <math.h>

#define BB 128   // batch
#define TT 256   // time
#define DD 256   // input dims
#define UU 512   // units
#define RR 512   // ladder order

// ws layout (floats):
//   X0 [128*512] @ 0        x_j lives in X[j&1]
//   X1 [128*512] @ 65536
//   M  [128*256] @ 131072   holds m_t while combo(t) runs
//   HZ [128*512] @ 163840   zeros (h_{-1})
#define OFF_X0 0
#define OFF_X1 65536
#define OFF_M  131072
#define OFF_HZ 163840
#define WS_FLT 229376
#define WS_NEED_BYTES (WS_FLT * 4)

__global__ __launch_bounds__(256) void zero_kernel(float* __restrict__ p, int n)
{
    int i = blockIdx.x * 256 + threadIdx.x;
    if (i < n) p[i] = 0.0f;
}

// combo(t): 256 blocks.
//   cg = bid&7  -> 64-col slice (XCD-aligned: round-robin dispatch puts cg==i on XCD i,
//                  so each XCD's L2 only holds its ~600KB weight slice, resident all run)
//   grp = bid>>3: grp<16 -> x-part rows, grp>=16 -> h-part rows (16 row-groups x 8 rows)
// 256 threads = 4 waves; wave -> 2 rows, lane -> 1 col.
//   x-part (t<=254): x_{t+1} = x_t @ AT + (inp_{t+1} + m_t) @ BT
//   h-part (t>=0):   h_t = tanh(((h_{t-1}@WyhT + x_t@WyxT) + (wfm*m_t)@WyfT) + by)
// Bitwise contract (matches np ref): each dot = ascending-k single-accumulator fmaf
// chain from 0.0f; combine order exactly as written in round 7. Unrolling and chain
// interleaving do NOT alter any chain's op sequence.
__global__ __launch_bounds__(256) void combo_kernel(
    const float* __restrict__ inputs, const float* __restrict__ wfm,
    const float* __restrict__ by,     const float* __restrict__ WyhT,
    const float* __restrict__ WyxT,   const float* __restrict__ WyfT,
    const float* __restrict__ AT,     const float* __restrict__ BT,
    const float* __restrict__ xin,    // x_t
    const float* __restrict__ m,      // m_t
    const float* __restrict__ hz,     // zeros
    float* __restrict__ xout,         // x_{t+1}
    float* __restrict__ out, int t)
{
    const int bid  = blockIdx.x;
    const int lane = threadIdx.x & 63;
    const int wv   = threadIdx.x >> 6;
    const int cg   = bid & 7;
    const int grp  = bid >> 3;
    const bool is_x = grp < 16;
    const int rg   = grp & 15;
    const int c    = cg * 64 + lane;
    const int r0   = rg * 8 + wv * 2;

    if (is_x) {
        if (t > TT - 2 && t != -1) return;
        if (t >= TT - 1) return;
        const float* x0 = xin + r0 * RR;
        const float* x1 = x0 + RR;
        float a0 = 0.0f, a1 = 0.0f;
        #pragma unroll 16
        for (int k = 0; k < RR; ++k) {
            float w = AT[k * RR + c];
            a0 = fmaf(x0[k], w, a0);
            a1 = fmaf(x1[k], w, a1);
        }
        const float* i0 = inputs + (r0 * TT + (t + 1)) * DD;
        const float* i1 = i0 + TT * DD;
        const float* m0 = m + r0 * DD;
        const float* m1 = m0 + DD;
        float b0 = 0.0f, b1 = 0.0f;
        #pragma unroll 16
        for (int d = 0; d < DD; ++d) {
            float w  = BT[d * RR + c];
            float u0 = i0[d] + m0[d];          // u = inp_{t+1} + m_t (one f32 round)
            float u1 = i1[d] + m1[d];
            b0 = fmaf(u0, w, b0);
            b1 = fmaf(u1, w, b1);
        }
        xout[r0 * RR + c]       = a0 + b0;     // dot + dot, one f32 add
        xout[(r0 + 1) * RR + c] = a1 + b1;
    } else {
        if (t < 0) return;
        const float* h0 = (t == 0) ? (hz + r0 * UU) : (out + (r0 * TT + (t - 1)) * UU);
        const float* h1 = (t == 0) ? (h0 + UU)      : (h0 + TT * UU);
        const float* x0 = xin + r0 * RR;
        const float* x1 = x0 + RR;
        float accH0 = 0.0f, accH1 = 0.0f, accX0 = 0.0f, accX1 = 0.0f;
        // Fused loop: accH and accX chains advance together (each chain's own
        // sequence remains ascending-k single-accumulator -> bitwise identical).
        #pragma unroll 8
        for (int k = 0; k < UU; ++k) {
            float wh = WyhT[k * UU + c];
            float wx = WyxT[k * UU + c];
            accH0 = fmaf(h0[k], wh, accH0);
            accH1 = fmaf(h1[k], wh, accH1);
            accX0 = fmaf(x0[k], wx, accX0);
            accX1 = fmaf(x1[k], wx, accX1);
        }
        const float* m0 = m + r0 * DD;
        const float* m1 = m0 + DD;
        float accF0 = 0.0f, accF1 = 0.0f;
        #pragma unroll 16
        for (int d = 0; d < DD; ++d) {
            float w  = WyfT[d * UU + c];
            float f0 = wfm[d] * m0[d];         // f = wfm * m_t (one f32 round)
            float f1 = wfm[d] * m1[d];
            accF0 = fmaf(f0, w, accF0);
            accF1 = fmaf(f1, w, accF1);
        }
        float z0 = ((accH0 + accX0) + accF0) + by[c];
        float z1 = ((accH1 + accX1) + accF1) + by[c];
        out[(r0 * TT + t) * UU + c]       = tanhf(z0);
        out[((r0 + 1) * TT + t) * UU + c] = tanhf(z1);
    }
}

// m_t = x_t @ CT. 128 blocks: cg = bid&7 (32-col slice), rg = bid>>3 (8 rows).
// wave -> 2 rows x 32 cols (lane>>5 = row parity, lane&31 = col).
__global__ __launch_bounds__(256) void m_kernel(
    const float* __restrict__ CT, const float* __restrict__ x,
    float* __restrict__ m)
{
    const int bid  = blockIdx.x;
    const int lane = threadIdx.x & 63;
    const int wv   = threadIdx.x >> 6;
    const int cg   = bid & 7;
    const int rg   = bid >> 3;
    const int row  = rg * 8 + wv * 2 + (lane >> 5);
    const int c    = cg * 32 + (lane & 31);
    const float* xr = x + row * RR;
    float acc = 0.0f;
    #pragma unroll 16
    for (int k = 0; k < RR; ++k)
        acc = fmaf(xr[k], CT[k * DD + c], acc);
    m[row * DD + c] = acc;
}

__global__ __launch_bounds__(64) void sentinel_kernel(float* __restrict__ out, float v)
{
    if (threadIdx.x == 0 && blockIdx.x == 0) out[0] = v;
}

extern "C" void kernel_launch(void* const* d_in, const int* in_sizes, int n_in,
                              void* d_out, int out_size, void* d_ws, size_t ws_size,
                              hipStream_t stream)
{
    const float* inputs = (const float*)d_in[0];
    const float* wfm    = (const float*)d_in[1];
    const float* WyhT   = (const float*)d_in[2];
    const float* WyxT   = (const float*)d_in[3];
    const float* WyfT   = (const float*)d_in[4];
    const float* by     = (const float*)d_in[5];
    const float* AT     = (const float*)d_in[6];
    const float* BT     = (const float*)d_in[7];
    const float* CT     = (const float*)d_in[8];
    float* out = (float*)d_out;
    float* ws  = (float*)d_ws;

    // Environment sentinels (absmax reveals code if triggered).
    double code = 0.0;
    static const int exp_sizes[9] = {8388608, 256, 262144, 262144, 131072,
                                     512, 262144, 131072, 131072};
    if (n_in != 9) {
        code = 3.0e6 + n_in;
    } else {
        for (int i = 0; i < 9; ++i)
            if (in_sizes[i] != exp_sizes[i]) { code = 2.0e6 + i * 1.0e4; break; }
    }
    if (code == 0.0 && out_size != BB * TT * UU)
        code = 4.0e6 + (double)(out_size / 10000);
    if (code == 0.0 && ws_size < (size_t)WS_NEED_BYTES)
        code = 1.0e6 + (double)(ws_size / 1024);
    if (code != 0.0) {
        sentinel_kernel<<<1, 64, 0, stream>>>(out, (float)code);
        return;
    }

    float* X0 = ws + OFF_X0;
    float* X1 = ws + OFF_X1;
    float* M  = ws + OFF_M;
    float* HZ = ws + OFF_HZ;

    // Zero X1 (x_{-1}), M (m_{-1}... unused), HZ (h_{-1}); X0 written before read.
    zero_kernel<<<(WS_FLT + 255) / 256, 256, 0, stream>>>(ws, WS_FLT);

    // combo(-1): x_0 = 0@AT + (inp_0 + 0)@BT   (h-part skipped; zero chains are bitwise-free)
    combo_kernel<<<256, 256, 0, stream>>>(inputs, wfm, by, WyhT, WyxT, WyfT, AT, BT,
                                          X1, M, HZ, X0, out, -1);
    m_kernel<<<128, 256, 0, stream>>>(CT, X0, M);   // m_0

    // t = 0..254: combo(t) = { h_t ; x_{t+1} }, then m_{t+1}.
    for (int t = 0; t < TT - 1; ++t) {
        float* xc = (t & 1) ? X1 : X0;   // x_t
        float* xn = (t & 1) ? X0 : X1;   // x_{t+1}
        combo_kernel<<<256, 256, 0, stream>>>(inputs, wfm, by, WyhT, WyxT, WyfT, AT, BT,
                                              xc, M, HZ, xn, out, t);
        m_kernel<<<128, 256, 0, stream>>>(CT, xn, M);  // m_{t+1}
    }
    // combo(255): h_255 only (x-part skipped). x_255 lives in X1 (255 odd).
    combo_kernel<<<256, 256, 0, stream>>>(inputs, wfm, by, WyhT, WyxT, WyfT, AT, BT,
                                          X1, M, HZ, X0, out, TT - 1);
}